// Round 1
// 419.179 us; speedup vs baseline: 1.5148x; 1.5148x over previous
//
#include <hip/hip_runtime.h>
#include <hip/hip_bf16.h>

// Problem constants (N=64, D=64, H=64, W=64, K=512)
#define VQ_D   64
#define VQ_K   512
#define VQ_HW  4096                 // H*W
#define VQ_M   262144               // N*H*W
#define VQ_MH  131072               // M/2 (two points per thread)
#define VQ_LOSS_OFF 16777216
#define VQ_IDX_OFF  16777217

// ---------------------------------------------------------------------------
// Kernel 1: e_sq[k] = sum_d emb[k][d]^2, replicating numpy's pairwise sum
// for n=64 (8 accumulators stride-8, then ((r0+r1)+(r2+r3))+((r4+r5)+(r6+r7))).
// ---------------------------------------------------------------------------
__global__ void vq_prep(const float* __restrict__ emb, float* __restrict__ esq) {
#pragma clang fp contract(off)
    int k = blockIdx.x * 256 + threadIdx.x;
    if (k < VQ_K) {
        const float* e = emb + k * VQ_D;
        float p[VQ_D];
#pragma unroll
        for (int d = 0; d < VQ_D; ++d) p[d] = e[d] * e[d];   // rounded products
        float r[8];
#pragma unroll
        for (int j = 0; j < 8; ++j) r[j] = p[j];
#pragma unroll
        for (int i = 8; i < VQ_D; i += 8)
#pragma unroll
            for (int j = 0; j < 8; ++j) r[j] += p[i + j];
        esq[k] = ((r[0] + r[1]) + (r[2] + r[3])) + ((r[4] + r[5]) + (r[6] + r[7]));
    }
}

// ---------------------------------------------------------------------------
// Kernel 2: main VQ. TWO spatial points per thread (m and m + M/2), so each
// wave-uniform codebook-row fetch (the latency bottleneck: chunked s_load of
// 512 B/iter from L2 that SGPR pressure prevents double-buffering) is
// amortized over 2x the FMAs, with 4 independent fma chains for ILP.
// Distance replicates the numpy fp32 reference BITWISE on the argmin path:
//   dist_k = fl( fl(z_sq + e_sq_k) - fl(2*dot_k) )
// with z_sq from numpy pairwise summation and dot_k a sequential fma chain
// (OpenBLAS sgemm microkernel order). Strict < keeps first occurrence.
// ---------------------------------------------------------------------------
__global__ __launch_bounds__(256, 3) void vq_main(
        const float* __restrict__ z_e,
        const float* __restrict__ emb,
        const float* __restrict__ esq,
        float* __restrict__ out,
        double* __restrict__ loss_acc)
{
#pragma clang fp contract(off)
    const int t  = blockIdx.x * 256 + threadIdx.x;   // < VQ_MH
    const int m0 = t;
    const int m1 = t + VQ_MH;
    const int n0 = m0 >> 12;                         // m / 4096
    const int hw0 = m0 & 4095;
    const int n1 = m1 >> 12;
    const int hw1 = m1 & 4095;

    const float* zp0 = z_e + (size_t)n0 * (VQ_D * VQ_HW) + hw0;
    const float* zp1 = z_e + (size_t)n1 * (VQ_D * VQ_HW) + hw1;
    float z0[VQ_D], z1[VQ_D];
#pragma unroll
    for (int d = 0; d < VQ_D; ++d) z0[d] = zp0[d * VQ_HW];  // coalesced per d
#pragma unroll
    for (int d = 0; d < VQ_D; ++d) z1[d] = zp1[d * VQ_HW];

    // ---- z_sq: numpy pairwise, n=64 path (per point, identical ordering) ----
    float zsq0, zsq1;
    {
        float p[VQ_D];
#pragma unroll
        for (int d = 0; d < VQ_D; ++d) p[d] = z0[d] * z0[d];
        float r[8];
#pragma unroll
        for (int j = 0; j < 8; ++j) r[j] = p[j];
#pragma unroll
        for (int i = 8; i < VQ_D; i += 8)
#pragma unroll
            for (int j = 0; j < 8; ++j) r[j] += p[i + j];
        zsq0 = ((r[0] + r[1]) + (r[2] + r[3])) + ((r[4] + r[5]) + (r[6] + r[7]));
    }
    {
        float p[VQ_D];
#pragma unroll
        for (int d = 0; d < VQ_D; ++d) p[d] = z1[d] * z1[d];
        float r[8];
#pragma unroll
        for (int j = 0; j < 8; ++j) r[j] = p[j];
#pragma unroll
        for (int i = 8; i < VQ_D; i += 8)
#pragma unroll
            for (int j = 0; j < 8; ++j) r[j] += p[i + j];
        zsq1 = ((r[0] + r[1]) + (r[2] + r[3])) + ((r[4] + r[5]) + (r[6] + r[7]));
    }

    // ---- argmin over K: 2 rows/trip, 2 points -> 4 independent fma chains ----
    float best0 = 3.4e38f, best1 = 3.4e38f;
    int   bi0   = 0,       bi1   = 0;
    for (int k = 0; k < VQ_K; k += 2) {
        const float* e0 = emb + k * VQ_D;            // wave-uniform -> s_load
        const float* e1 = e0 + VQ_D;
        float a00 = 0.f, a01 = 0.f, a10 = 0.f, a11 = 0.f;
#pragma unroll
        for (int d = 0; d < VQ_D; ++d) {
            const float ev0 = e0[d];
            const float ev1 = e1[d];
            a00 = __builtin_fmaf(z0[d], ev0, a00);   // sequential fma chains
            a10 = __builtin_fmaf(z1[d], ev0, a10);
            a01 = __builtin_fmaf(z0[d], ev1, a01);
            a11 = __builtin_fmaf(z1[d], ev1, a11);
        }
        const float es0 = esq[k];
        const float es1 = esq[k + 1];
        float d00 = (zsq0 + es0) - 2.0f * a00;       // fl(t - 2*dot), 2*dot exact
        float d01 = (zsq0 + es1) - 2.0f * a01;
        float d10 = (zsq1 + es0) - 2.0f * a10;
        float d11 = (zsq1 + es1) - 2.0f * a11;
        if (d00 < best0) { best0 = d00; bi0 = k;     }  // strict <: first occurrence
        if (d01 < best0) { best0 = d01; bi0 = k + 1; }
        if (d10 < best1) { best1 = d10; bi1 = k;     }
        if (d11 < best1) { best1 = d11; bi1 = k + 1; }
    }

    // ---- gather winning rows, write z_q + indices, accumulate loss ----
    float lsum = 0.f;
    {
        const float* eb = emb + bi0 * VQ_D;
        float* op = out + (size_t)n0 * (VQ_D * VQ_HW) + hw0;
#pragma unroll
        for (int d = 0; d < VQ_D; ++d) {
            float q = eb[d];
            op[d * VQ_HW] = q;                       // coalesced across lanes
            float diff = z0[d] - q;
            lsum = __builtin_fmaf(diff, diff, lsum);
        }
    }
    {
        const float* eb = emb + bi1 * VQ_D;
        float* op = out + (size_t)n1 * (VQ_D * VQ_HW) + hw1;
#pragma unroll
        for (int d = 0; d < VQ_D; ++d) {
            float q = eb[d];
            op[d * VQ_HW] = q;
            float diff = z1[d] - q;
            lsum = __builtin_fmaf(diff, diff, lsum);
        }
    }

    out[VQ_IDX_OFF + m0] = (float)bi0;               // indices as f32 values
    out[VQ_IDX_OFF + m1] = (float)bi1;

    // ---- loss reduction: wave shuffle -> LDS -> one atomic per block ----
    for (int off = 32; off > 0; off >>= 1)
        lsum += __shfl_down(lsum, off, 64);

    __shared__ float wsum[4];
    const int lane = threadIdx.x & 63;
    const int wid  = threadIdx.x >> 6;
    if (lane == 0) wsum[wid] = lsum;
    __syncthreads();
    if (threadIdx.x == 0) {
        float b = wsum[0] + wsum[1] + wsum[2] + wsum[3];
        atomicAdd(loss_acc, (double)b);
    }
}

// ---------------------------------------------------------------------------
// Kernel 3: finalize loss (mean over M*D = 16777216 elements).
// ---------------------------------------------------------------------------
__global__ void vq_fin(const double* __restrict__ loss_acc, float* __restrict__ out) {
    if (threadIdx.x == 0)
        out[VQ_LOSS_OFF] = (float)(*loss_acc / 16777216.0);
}

extern "C" void kernel_launch(void* const* d_in, const int* in_sizes, int n_in,
                              void* d_out, int out_size, void* d_ws, size_t ws_size,
                              hipStream_t stream) {
    const float* z_e = (const float*)d_in[0];
    const float* emb = (const float*)d_in[1];
    float* out = (float*)d_out;

    // ws layout: [0,8) double loss accumulator, [8, 8+2048) float esq[512]
    double* loss_acc = (double*)d_ws;
    float*  esq      = (float*)((char*)d_ws + 8);

    (void)hipMemsetAsync(d_ws, 0, 8, stream);
    vq_prep<<<2, 256, 0, stream>>>(emb, esq);
    vq_main<<<VQ_MH / 256, 256, 0, stream>>>(z_e, emb, esq, out, loss_acc);
    vq_fin<<<1, 64, 0, stream>>>(loss_acc, out);
}

// Round 2
// 387.791 us; speedup vs baseline: 1.6374x; 1.0809x over previous
//
#include <hip/hip_runtime.h>
#include <hip/hip_bf16.h>

// Problem constants (N=64, D=64, H=64, W=64, K=512)
#define VQ_D   64
#define VQ_K   512
#define VQ_HW  4096                 // H*W
#define VQ_M   262144               // N*H*W
#define VQ_MH  131072               // M/2 (two points per thread)
#define VQ_LOSS_OFF 16777216
#define VQ_IDX_OFF  16777217

// ---------------------------------------------------------------------------
// Kernel 1: e_sq[k] = sum_d emb[k][d]^2, replicating numpy's pairwise sum
// for n=64 (8 accumulators stride-8, then ((r0+r1)+(r2+r3))+((r4+r5)+(r6+r7))).
// ---------------------------------------------------------------------------
__global__ void vq_prep(const float* __restrict__ emb, float* __restrict__ esq) {
#pragma clang fp contract(off)
    int k = blockIdx.x * 256 + threadIdx.x;
    if (k < VQ_K) {
        const float* e = emb + k * VQ_D;
        float p[VQ_D];
#pragma unroll
        for (int d = 0; d < VQ_D; ++d) p[d] = e[d] * e[d];   // rounded products
        float r[8];
#pragma unroll
        for (int j = 0; j < 8; ++j) r[j] = p[j];
#pragma unroll
        for (int i = 8; i < VQ_D; i += 8)
#pragma unroll
            for (int j = 0; j < 8; ++j) r[j] += p[i + j];
        esq[k] = ((r[0] + r[1]) + (r[2] + r[3])) + ((r[4] + r[5]) + (r[6] + r[7]));
    }
}

// ---------------------------------------------------------------------------
// Kernel 2: main VQ. TWO spatial points per thread (m and m + M/2).
// Codebook fetch is split across two independent load pipes to hide latency:
//   - even rows k: wave-uniform global reads -> s_load (scalar K$ pipe,
//     64 SGPRs/row, one-row prefetch now fits the SGPR budget)
//   - odd rows k: staged once into LDS (64 KB/block) -> ds_read_b128
//     broadcast reads, deeply pipelined via fine-grained lgkmcnt
// Distance replicates the numpy fp32 reference BITWISE on the argmin path:
//   dist_k = fl( fl(z_sq + e_sq_k) - fl(2*dot_k) )
// with z_sq from numpy pairwise summation and dot_k a sequential fma chain
// (OpenBLAS sgemm microkernel order). Strict < keeps first occurrence.
// ---------------------------------------------------------------------------
__global__ __launch_bounds__(256, 2) void vq_main(
        const float* __restrict__ z_e,
        const float* __restrict__ emb,
        const float* __restrict__ esq,
        float* __restrict__ out,
        double* __restrict__ loss_acc)
{
#pragma clang fp contract(off)
    __shared__ float lds_e[256 * VQ_D];              // odd rows: 64 KB

    const int t  = blockIdx.x * 256 + threadIdx.x;   // < VQ_MH
    const int m0 = t;
    const int m1 = t + VQ_MH;
    const int n0 = m0 >> 12;                         // m / 4096
    const int hw0 = m0 & 4095;
    const int n1 = m1 >> 12;
    const int hw1 = m1 & 4095;

    // ---- stage odd codebook rows into LDS (identical bits, coalesced) ----
    // 256 odd rows * 256 B = 64 KB = 4096 float4 chunks; 16 chunks/thread.
    {
        float4* lds4 = reinterpret_cast<float4*>(lds_e);
#pragma unroll
        for (int i = 0; i < 16; ++i) {
            const int c = threadIdx.x + i * 256;     // chunk id 0..4095
            const int row = c >> 4;                  // lds row 0..255
            const int q   = c & 15;                  // float4 within row
            lds4[c] = *reinterpret_cast<const float4*>(
                emb + (2 * row + 1) * VQ_D + q * 4);
        }
    }

    const float* zp0 = z_e + (size_t)n0 * (VQ_D * VQ_HW) + hw0;
    const float* zp1 = z_e + (size_t)n1 * (VQ_D * VQ_HW) + hw1;
    float z0[VQ_D], z1[VQ_D];
#pragma unroll
    for (int d = 0; d < VQ_D; ++d) z0[d] = zp0[d * VQ_HW];  // coalesced per d
#pragma unroll
    for (int d = 0; d < VQ_D; ++d) z1[d] = zp1[d * VQ_HW];

    // ---- z_sq: numpy pairwise, n=64 path (per point, identical ordering) ----
    float zsq0, zsq1;
    {
        float p[VQ_D];
#pragma unroll
        for (int d = 0; d < VQ_D; ++d) p[d] = z0[d] * z0[d];
        float r[8];
#pragma unroll
        for (int j = 0; j < 8; ++j) r[j] = p[j];
#pragma unroll
        for (int i = 8; i < VQ_D; i += 8)
#pragma unroll
            for (int j = 0; j < 8; ++j) r[j] += p[i + j];
        zsq0 = ((r[0] + r[1]) + (r[2] + r[3])) + ((r[4] + r[5]) + (r[6] + r[7]));
    }
    {
        float p[VQ_D];
#pragma unroll
        for (int d = 0; d < VQ_D; ++d) p[d] = z1[d] * z1[d];
        float r[8];
#pragma unroll
        for (int j = 0; j < 8; ++j) r[j] = p[j];
#pragma unroll
        for (int i = 8; i < VQ_D; i += 8)
#pragma unroll
            for (int j = 0; j < 8; ++j) r[j] += p[i + j];
        zsq1 = ((r[0] + r[1]) + (r[2] + r[3])) + ((r[4] + r[5]) + (r[6] + r[7]));
    }

    __syncthreads();                                 // LDS codebook ready

    // ---- argmin over K: 2 rows/trip (even: s_load, odd: LDS),
    //      2 points -> 4 independent fma chains ----
    float best0 = 3.4e38f, best1 = 3.4e38f;
    int   bi0   = 0,       bi1   = 0;
    for (int k = 0; k < VQ_K; k += 2) {
        const float* e0 = emb + k * VQ_D;            // wave-uniform -> s_load
        const float* l1 = lds_e + (k >> 1) * VQ_D;   // odd row from LDS
        float a00 = 0.f, a01 = 0.f, a10 = 0.f, a11 = 0.f;
#pragma unroll
        for (int d = 0; d < VQ_D; ++d) {
            const float ev0 = e0[d];
            const float ev1 = l1[d];
            a00 = __builtin_fmaf(z0[d], ev0, a00);   // sequential fma chains
            a10 = __builtin_fmaf(z1[d], ev0, a10);
            a01 = __builtin_fmaf(z0[d], ev1, a01);
            a11 = __builtin_fmaf(z1[d], ev1, a11);
        }
        const float es0 = esq[k];
        const float es1 = esq[k + 1];
        float d00 = (zsq0 + es0) - 2.0f * a00;       // fl(t - 2*dot), 2*dot exact
        float d01 = (zsq0 + es1) - 2.0f * a01;
        float d10 = (zsq1 + es0) - 2.0f * a10;
        float d11 = (zsq1 + es1) - 2.0f * a11;
        if (d00 < best0) { best0 = d00; bi0 = k;     }  // strict <: first occurrence
        if (d01 < best0) { best0 = d01; bi0 = k + 1; }
        if (d10 < best1) { best1 = d10; bi1 = k;     }
        if (d11 < best1) { best1 = d11; bi1 = k + 1; }
    }

    // ---- gather winning rows, write z_q + indices, accumulate loss ----
    float lsum = 0.f;
    {
        const float* eb = emb + bi0 * VQ_D;
        float* op = out + (size_t)n0 * (VQ_D * VQ_HW) + hw0;
#pragma unroll
        for (int d = 0; d < VQ_D; ++d) {
            float q = eb[d];
            op[d * VQ_HW] = q;                       // coalesced across lanes
            float diff = z0[d] - q;
            lsum = __builtin_fmaf(diff, diff, lsum);
        }
    }
    {
        const float* eb = emb + bi1 * VQ_D;
        float* op = out + (size_t)n1 * (VQ_D * VQ_HW) + hw1;
#pragma unroll
        for (int d = 0; d < VQ_D; ++d) {
            float q = eb[d];
            op[d * VQ_HW] = q;
            float diff = z1[d] - q;
            lsum = __builtin_fmaf(diff, diff, lsum);
        }
    }

    out[VQ_IDX_OFF + m0] = (float)bi0;               // indices as f32 values
    out[VQ_IDX_OFF + m1] = (float)bi1;

    // ---- loss reduction: wave shuffle -> LDS -> one atomic per block ----
    for (int off = 32; off > 0; off >>= 1)
        lsum += __shfl_down(lsum, off, 64);

    __shared__ float wsum[4];
    const int lane = threadIdx.x & 63;
    const int wid  = threadIdx.x >> 6;
    if (lane == 0) wsum[wid] = lsum;
    __syncthreads();
    if (threadIdx.x == 0) {
        float b = wsum[0] + wsum[1] + wsum[2] + wsum[3];
        atomicAdd(loss_acc, (double)b);
    }
}

// ---------------------------------------------------------------------------
// Kernel 3: finalize loss (mean over M*D = 16777216 elements).
// ---------------------------------------------------------------------------
__global__ void vq_fin(const double* __restrict__ loss_acc, float* __restrict__ out) {
    if (threadIdx.x == 0)
        out[VQ_LOSS_OFF] = (float)(*loss_acc / 16777216.0);
}

extern "C" void kernel_launch(void* const* d_in, const int* in_sizes, int n_in,
                              void* d_out, int out_size, void* d_ws, size_t ws_size,
                              hipStream_t stream) {
    const float* z_e = (const float*)d_in[0];
    const float* emb = (const float*)d_in[1];
    float* out = (float*)d_out;

    // ws layout: [0,8) double loss accumulator, [8, 8+2048) float esq[512]
    double* loss_acc = (double*)d_ws;
    float*  esq      = (float*)((char*)d_ws + 8);

    (void)hipMemsetAsync(d_ws, 0, 8, stream);
    vq_prep<<<2, 256, 0, stream>>>(emb, esq);
    vq_main<<<VQ_MH / 256, 256, 0, stream>>>(z_e, emb, esq, out, loss_acc);
    vq_fin<<<1, 64, 0, stream>>>(loss_acc, out);
}

// Round 3
// 351.175 us; speedup vs baseline: 1.8082x; 1.1043x over previous
//
#include <hip/hip_runtime.h>
#include <hip/hip_bf16.h>

// Problem constants (N=64, D=64, H=64, W=64, K=512)
#define VQ_D   64
#define VQ_K   512
#define VQ_HW  4096                 // H*W
#define VQ_M   262144               // N*H*W
#define VQ_MH  131072               // M/2 (two points per thread)
#define VQ_LOSS_OFF 16777216
#define VQ_IDX_OFF  16777217

// ---------------------------------------------------------------------------
// Kernel 1: e_sq[k] = sum_d emb[k][d]^2, replicating numpy's pairwise sum
// for n=64 (8 accumulators stride-8, then ((r0+r1)+(r2+r3))+((r4+r5)+(r6+r7))).
// ---------------------------------------------------------------------------
__global__ void vq_prep(const float* __restrict__ emb, float* __restrict__ esq) {
#pragma clang fp contract(off)
    int k = blockIdx.x * 256 + threadIdx.x;
    if (k < VQ_K) {
        const float* e = emb + k * VQ_D;
        float p[VQ_D];
#pragma unroll
        for (int d = 0; d < VQ_D; ++d) p[d] = e[d] * e[d];   // rounded products
        float r[8];
#pragma unroll
        for (int j = 0; j < 8; ++j) r[j] = p[j];
#pragma unroll
        for (int i = 8; i < VQ_D; i += 8)
#pragma unroll
            for (int j = 0; j < 8; ++j) r[j] += p[i + j];
        esq[k] = ((r[0] + r[1]) + (r[2] + r[3])) + ((r[4] + r[5]) + (r[6] + r[7]));
    }
}

// ---------------------------------------------------------------------------
// Kernel 2: main VQ. TWO spatial points per thread (m and m + M/2).
// ALL codebook rows come from LDS (no scalar s_load data path — the 102-SGPR
// budget cannot double-buffer a 64-float row, so the scalar path chunks
// load->lgkmcnt->use and re-exposes K$ latency every trip; that was ~50% of
// wall time). LDS (64 KB) holds half the codebook; K is walked in two
// sequential phases with a cooperative restage between them. Inner loop is
// 32 uniform broadcast ds_read_b128 + 256 fma per trip, pipelined by the
// compiler's fine-grained lgkmcnt under the fma issue stream.
// Distance replicates the numpy fp32 reference BITWISE on the argmin path:
//   dist_k = fl( fl(z_sq + e_sq_k) - fl(2*dot_k) )
// with z_sq from numpy pairwise summation and dot_k a sequential fma chain
// (OpenBLAS sgemm microkernel order). Strict < keeps first occurrence.
// ---------------------------------------------------------------------------
__global__ __launch_bounds__(256, 2) void vq_main(
        const float* __restrict__ z_e,
        const float* __restrict__ emb,
        const float* __restrict__ esq,
        float* __restrict__ out,
        double* __restrict__ loss_acc)
{
#pragma clang fp contract(off)
    __shared__ float lds_e[256 * VQ_D];              // current phase rows: 64 KB

    const int t  = blockIdx.x * 256 + threadIdx.x;   // < VQ_MH
    const int m0 = t;
    const int m1 = t + VQ_MH;
    const int n0 = m0 >> 12;                         // m / 4096
    const int hw0 = m0 & 4095;
    const int n1 = m1 >> 12;
    const int hw1 = m1 & 4095;

    const float* zp0 = z_e + (size_t)n0 * (VQ_D * VQ_HW) + hw0;
    const float* zp1 = z_e + (size_t)n1 * (VQ_D * VQ_HW) + hw1;
    float z0[VQ_D], z1[VQ_D];
#pragma unroll
    for (int d = 0; d < VQ_D; ++d) z0[d] = zp0[d * VQ_HW];  // coalesced per d
#pragma unroll
    for (int d = 0; d < VQ_D; ++d) z1[d] = zp1[d * VQ_HW];

    // ---- z_sq: numpy pairwise, n=64 path (per point, identical ordering) ----
    float zsq0, zsq1;
    {
        float p[VQ_D];
#pragma unroll
        for (int d = 0; d < VQ_D; ++d) p[d] = z0[d] * z0[d];
        float r[8];
#pragma unroll
        for (int j = 0; j < 8; ++j) r[j] = p[j];
#pragma unroll
        for (int i = 8; i < VQ_D; i += 8)
#pragma unroll
            for (int j = 0; j < 8; ++j) r[j] += p[i + j];
        zsq0 = ((r[0] + r[1]) + (r[2] + r[3])) + ((r[4] + r[5]) + (r[6] + r[7]));
    }
    {
        float p[VQ_D];
#pragma unroll
        for (int d = 0; d < VQ_D; ++d) p[d] = z1[d] * z1[d];
        float r[8];
#pragma unroll
        for (int j = 0; j < 8; ++j) r[j] = p[j];
#pragma unroll
        for (int i = 8; i < VQ_D; i += 8)
#pragma unroll
            for (int j = 0; j < 8; ++j) r[j] += p[i + j];
        zsq1 = ((r[0] + r[1]) + (r[2] + r[3])) + ((r[4] + r[5]) + (r[6] + r[7]));
    }

    // ---- argmin over K in two LDS phases of 256 rows each ----
    float best0 = 3.4e38f, best1 = 3.4e38f;
    int   bi0   = 0,       bi1   = 0;

    for (int ph = 0; ph < 2; ++ph) {
        __syncthreads();                             // all readers done w/ LDS
        {
            // stage rows [ph*256, ph*256+256): 4096 float4, 16 per thread,
            // fully coalesced, identical bits, linear row-major layout
            float4* lds4 = reinterpret_cast<float4*>(lds_e);
            const float4* src = reinterpret_cast<const float4*>(emb)
                                + ph * (256 * VQ_D / 4);
#pragma unroll
            for (int i = 0; i < 16; ++i) {
                const int c = threadIdx.x + i * 256;
                lds4[c] = src[c];
            }
        }
        __syncthreads();                             // LDS codebook ready

        const int base = ph * 256;
        for (int kk = 0; kk < 256; kk += 2) {
            const float* l0 = lds_e + kk * VQ_D;     // wave-uniform -> broadcast
            const float* l1 = l0 + VQ_D;
            float a00 = 0.f, a01 = 0.f, a10 = 0.f, a11 = 0.f;
#pragma unroll
            for (int d = 0; d < VQ_D; ++d) {
                const float ev0 = l0[d];
                const float ev1 = l1[d];
                a00 = __builtin_fmaf(z0[d], ev0, a00);   // sequential fma chains
                a10 = __builtin_fmaf(z1[d], ev0, a10);
                a01 = __builtin_fmaf(z0[d], ev1, a01);
                a11 = __builtin_fmaf(z1[d], ev1, a11);
            }
            const int k = base + kk;
            const float es0 = esq[k];
            const float es1 = esq[k + 1];
            float d00 = (zsq0 + es0) - 2.0f * a00;   // fl(t - 2*dot), 2*dot exact
            float d01 = (zsq0 + es1) - 2.0f * a01;
            float d10 = (zsq1 + es0) - 2.0f * a10;
            float d11 = (zsq1 + es1) - 2.0f * a11;
            if (d00 < best0) { best0 = d00; bi0 = k;     }  // strict <: first occ.
            if (d01 < best0) { best0 = d01; bi0 = k + 1; }
            if (d10 < best1) { best1 = d10; bi1 = k;     }
            if (d11 < best1) { best1 = d11; bi1 = k + 1; }
        }
    }

    // ---- gather winning rows, write z_q + indices, accumulate loss ----
    float lsum = 0.f;
    {
        const float* eb = emb + bi0 * VQ_D;
        float* op = out + (size_t)n0 * (VQ_D * VQ_HW) + hw0;
#pragma unroll
        for (int d = 0; d < VQ_D; ++d) {
            float q = eb[d];
            op[d * VQ_HW] = q;                       // coalesced across lanes
            float diff = z0[d] - q;
            lsum = __builtin_fmaf(diff, diff, lsum);
        }
    }
    {
        const float* eb = emb + bi1 * VQ_D;
        float* op = out + (size_t)n1 * (VQ_D * VQ_HW) + hw1;
#pragma unroll
        for (int d = 0; d < VQ_D; ++d) {
            float q = eb[d];
            op[d * VQ_HW] = q;
            float diff = z1[d] - q;
            lsum = __builtin_fmaf(diff, diff, lsum);
        }
    }

    out[VQ_IDX_OFF + m0] = (float)bi0;               // indices as f32 values
    out[VQ_IDX_OFF + m1] = (float)bi1;

    // ---- loss reduction: wave shuffle -> LDS -> one atomic per block ----
    for (int off = 32; off > 0; off >>= 1)
        lsum += __shfl_down(lsum, off, 64);

    __shared__ float wsum[4];
    const int lane = threadIdx.x & 63;
    const int wid  = threadIdx.x >> 6;
    if (lane == 0) wsum[wid] = lsum;
    __syncthreads();
    if (threadIdx.x == 0) {
        float b = wsum[0] + wsum[1] + wsum[2] + wsum[3];
        atomicAdd(loss_acc, (double)b);
    }
}

// ---------------------------------------------------------------------------
// Kernel 3: finalize loss (mean over M*D = 16777216 elements).
// ---------------------------------------------------------------------------
__global__ void vq_fin(const double* __restrict__ loss_acc, float* __restrict__ out) {
    if (threadIdx.x == 0)
        out[VQ_LOSS_OFF] = (float)(*loss_acc / 16777216.0);
}

extern "C" void kernel_launch(void* const* d_in, const int* in_sizes, int n_in,
                              void* d_out, int out_size, void* d_ws, size_t ws_size,
                              hipStream_t stream) {
    const float* z_e = (const float*)d_in[0];
    const float* emb = (const float*)d_in[1];
    float* out = (float*)d_out;

    // ws layout: [0,8) double loss accumulator, [8, 8+2048) float esq[512]
    double* loss_acc = (double*)d_ws;
    float*  esq      = (float*)((char*)d_ws + 8);

    (void)hipMemsetAsync(d_ws, 0, 8, stream);
    vq_prep<<<2, 256, 0, stream>>>(emb, esq);
    vq_main<<<VQ_MH / 256, 256, 0, stream>>>(z_e, emb, esq, out, loss_acc);
    vq_fin<<<1, 64, 0, stream>>>(loss_acc, out);
}

// Round 4
// 334.058 us; speedup vs baseline: 1.9008x; 1.0512x over previous
//
#include <hip/hip_runtime.h>
#include <hip/hip_bf16.h>

// Problem constants (N=64, D=64, H=64, W=64, K=512)
#define VQ_D   64
#define VQ_K   512
#define VQ_HW  4096                 // H*W
#define VQ_M   262144               // N*H*W
#define VQ_MH  131072               // M/2 (two points per thread)
#define VQ_LOSS_OFF 16777216
#define VQ_IDX_OFF  16777217

typedef float f4v __attribute__((ext_vector_type(4)));

// ---------------------------------------------------------------------------
// Kernel 1: e_sq[k] = sum_d emb[k][d]^2, replicating numpy's pairwise sum
// for n=64 (8 accumulators stride-8, then ((r0+r1)+(r2+r3))+((r4+r5)+(r6+r7))).
// ---------------------------------------------------------------------------
__global__ void vq_prep(const float* __restrict__ emb, float* __restrict__ esq) {
#pragma clang fp contract(off)
    int k = blockIdx.x * 256 + threadIdx.x;
    if (k < VQ_K) {
        const float* e = emb + k * VQ_D;
        float p[VQ_D];
#pragma unroll
        for (int d = 0; d < VQ_D; ++d) p[d] = e[d] * e[d];   // rounded products
        float r[8];
#pragma unroll
        for (int j = 0; j < 8; ++j) r[j] = p[j];
#pragma unroll
        for (int i = 8; i < VQ_D; i += 8)
#pragma unroll
            for (int j = 0; j < 8; ++j) r[j] += p[i + j];
        esq[k] = ((r[0] + r[1]) + (r[2] + r[3])) + ((r[4] + r[5]) + (r[6] + r[7]));
    }
}

// ---------------------------------------------------------------------------
// Kernel 2: main VQ. TWO spatial points per thread (m and m + M/2).
// All codebook rows come from LDS (64 KB = half the codebook, two phases).
// The inner loop is explicitly software-pipelined at 16-d chunk granularity:
// a double-buffered register e-buffer (ebuf[2][8] float4) holds the current
// chunk while the next chunk's 8 ds_read_b128 are in flight, so the ~120 cyc
// LDS latency hides under 128 cyc of fma issue per chunk (2x with TLP).
// Distance replicates the numpy fp32 reference BITWISE on the argmin path:
//   dist_k = fl( fl(z_sq + e_sq_k) - fl(2*dot_k) )
// with z_sq from numpy pairwise summation and dot_k a sequential fma chain
// in ascending d order (d = c*16 + j*4 + x covers 0..63 in order — identical
// chain to the reference). Strict < keeps first occurrence.
// ---------------------------------------------------------------------------
__global__ __launch_bounds__(256, 2) void vq_main(
        const float* __restrict__ z_e,
        const float* __restrict__ emb,
        const float* __restrict__ esq,
        float* __restrict__ out,
        double* __restrict__ loss_acc)
{
#pragma clang fp contract(off)
    __shared__ float lds_e[256 * VQ_D];              // current phase rows: 64 KB

    const int t  = blockIdx.x * 256 + threadIdx.x;   // < VQ_MH
    const int m0 = t;
    const int m1 = t + VQ_MH;
    const int n0 = m0 >> 12;                         // m / 4096
    const int hw0 = m0 & 4095;
    const int n1 = m1 >> 12;
    const int hw1 = m1 & 4095;

    const float* zp0 = z_e + (size_t)n0 * (VQ_D * VQ_HW) + hw0;
    const float* zp1 = z_e + (size_t)n1 * (VQ_D * VQ_HW) + hw1;
    float z0[VQ_D], z1[VQ_D];
#pragma unroll
    for (int d = 0; d < VQ_D; ++d) z0[d] = zp0[d * VQ_HW];  // coalesced per d
#pragma unroll
    for (int d = 0; d < VQ_D; ++d) z1[d] = zp1[d * VQ_HW];

    // ---- z_sq: numpy pairwise, n=64 path (per point, identical ordering) ----
    float zsq0, zsq1;
    {
        float p[VQ_D];
#pragma unroll
        for (int d = 0; d < VQ_D; ++d) p[d] = z0[d] * z0[d];
        float r[8];
#pragma unroll
        for (int j = 0; j < 8; ++j) r[j] = p[j];
#pragma unroll
        for (int i = 8; i < VQ_D; i += 8)
#pragma unroll
            for (int j = 0; j < 8; ++j) r[j] += p[i + j];
        zsq0 = ((r[0] + r[1]) + (r[2] + r[3])) + ((r[4] + r[5]) + (r[6] + r[7]));
    }
    {
        float p[VQ_D];
#pragma unroll
        for (int d = 0; d < VQ_D; ++d) p[d] = z1[d] * z1[d];
        float r[8];
#pragma unroll
        for (int j = 0; j < 8; ++j) r[j] = p[j];
#pragma unroll
        for (int i = 8; i < VQ_D; i += 8)
#pragma unroll
            for (int j = 0; j < 8; ++j) r[j] += p[i + j];
        zsq1 = ((r[0] + r[1]) + (r[2] + r[3])) + ((r[4] + r[5]) + (r[6] + r[7]));
    }

    // ---- argmin over K in two LDS phases of 256 rows each ----
    float best0 = 3.4e38f, best1 = 3.4e38f;
    int   bi0   = 0,       bi1   = 0;

    for (int ph = 0; ph < 2; ++ph) {
        __syncthreads();                             // all readers done w/ LDS
        {
            // stage rows [ph*256, ph*256+256): 4096 float4, 16 per thread,
            // fully coalesced, identical bits, linear row-major layout
            f4v* lds4w = reinterpret_cast<f4v*>(lds_e);
            const f4v* src = reinterpret_cast<const f4v*>(emb)
                             + ph * (256 * VQ_D / 4);
#pragma unroll
            for (int i = 0; i < 16; ++i) {
                const int c = threadIdx.x + i * 256;
                lds4w[c] = src[c];
            }
        }
        __syncthreads();                             // LDS codebook ready

        const f4v* lds4 = reinterpret_cast<const f4v*>(lds_e);
        const int base = ph * 256;

        // ebuf[parity][0..3] = row 2t  d-chunk, ebuf[parity][4..7] = row 2t+1.
        // parity = chunk&1 (4 chunks/trip -> global chunk parity == c&1).
        f4v ebuf[2][8];
        // preload chunk 0 of trip 0 (rows 0,1 of this phase, d 0..15)
#pragma unroll
        for (int j = 0; j < 4; ++j) {
            ebuf[0][j]     = lds4[j];                // row 0, float4 j
            ebuf[0][4 + j] = lds4[16 + j];           // row 1, float4 j
        }

        for (int tt = 0; tt < 128; ++tt) {
            float a00 = 0.f, a01 = 0.f, a10 = 0.f, a11 = 0.f;
#pragma unroll
            for (int c = 0; c < 4; ++c) {
                const int p = c & 1;
                // issue next chunk's 8 ds_read_b128 into the other buffer
                const int gn = tt * 4 + c + 1;       // next global chunk id
                if (gn < 512) {
                    const int tn = gn >> 2;          // next trip
                    const int cn = gn & 3;           // next chunk within trip
                    const int b0 = 32 * tn + 4 * cn; // float4 index of row 2tn
#pragma unroll
                    for (int j = 0; j < 4; ++j) {
                        ebuf[p ^ 1][j]     = lds4[b0 + j];
                        ebuf[p ^ 1][4 + j] = lds4[b0 + 16 + j];
                    }
                }
                // compute 64 fmas on current chunk (d ascending: bitwise chain)
#pragma unroll
                for (int j = 0; j < 4; ++j) {
#pragma unroll
                    for (int x = 0; x < 4; ++x) {
                        const int d = c * 16 + j * 4 + x;
                        const float ev0 = ebuf[p][j][x];
                        const float ev1 = ebuf[p][4 + j][x];
                        a00 = __builtin_fmaf(z0[d], ev0, a00);
                        a10 = __builtin_fmaf(z1[d], ev0, a10);
                        a01 = __builtin_fmaf(z0[d], ev1, a01);
                        a11 = __builtin_fmaf(z1[d], ev1, a11);
                    }
                }
            }
            const int k = base + 2 * tt;
            const float es0 = esq[k];
            const float es1 = esq[k + 1];
            float d00 = (zsq0 + es0) - 2.0f * a00;   // fl(t - 2*dot), 2*dot exact
            float d01 = (zsq0 + es1) - 2.0f * a01;
            float d10 = (zsq1 + es0) - 2.0f * a10;
            float d11 = (zsq1 + es1) - 2.0f * a11;
            if (d00 < best0) { best0 = d00; bi0 = k;     }  // strict <: first occ.
            if (d01 < best0) { best0 = d01; bi0 = k + 1; }
            if (d10 < best1) { best1 = d10; bi1 = k;     }
            if (d11 < best1) { best1 = d11; bi1 = k + 1; }
        }
    }

    // ---- gather winning rows, write z_q + indices, accumulate loss ----
    float lsum = 0.f;
    {
        const float* eb = emb + bi0 * VQ_D;
        float* op = out + (size_t)n0 * (VQ_D * VQ_HW) + hw0;
#pragma unroll
        for (int d = 0; d < VQ_D; ++d) {
            float q = eb[d];
            op[d * VQ_HW] = q;                       // coalesced across lanes
            float diff = z0[d] - q;
            lsum = __builtin_fmaf(diff, diff, lsum);
        }
    }
    {
        const float* eb = emb + bi1 * VQ_D;
        float* op = out + (size_t)n1 * (VQ_D * VQ_HW) + hw1;
#pragma unroll
        for (int d = 0; d < VQ_D; ++d) {
            float q = eb[d];
            op[d * VQ_HW] = q;
            float diff = z1[d] - q;
            lsum = __builtin_fmaf(diff, diff, lsum);
        }
    }

    out[VQ_IDX_OFF + m0] = (float)bi0;               // indices as f32 values
    out[VQ_IDX_OFF + m1] = (float)bi1;

    // ---- loss reduction: wave shuffle -> LDS -> one atomic per block ----
    for (int off = 32; off > 0; off >>= 1)
        lsum += __shfl_down(lsum, off, 64);

    __shared__ float wsum[4];
    const int lane = threadIdx.x & 63;
    const int wid  = threadIdx.x >> 6;
    if (lane == 0) wsum[wid] = lsum;
    __syncthreads();
    if (threadIdx.x == 0) {
        float b = wsum[0] + wsum[1] + wsum[2] + wsum[3];
        atomicAdd(loss_acc, (double)b);
    }
}

// ---------------------------------------------------------------------------
// Kernel 3: finalize loss (mean over M*D = 16777216 elements).
// ---------------------------------------------------------------------------
__global__ void vq_fin(const double* __restrict__ loss_acc, float* __restrict__ out) {
    if (threadIdx.x == 0)
        out[VQ_LOSS_OFF] = (float)(*loss_acc / 16777216.0);
}

extern "C" void kernel_launch(void* const* d_in, const int* in_sizes, int n_in,
                              void* d_out, int out_size, void* d_ws, size_t ws_size,
                              hipStream_t stream) {
    const float* z_e = (const float*)d_in[0];
    const float* emb = (const float*)d_in[1];
    float* out = (float*)d_out;

    // ws layout: [0,8) double loss accumulator, [8, 8+2048) float esq[512]
    double* loss_acc = (double*)d_ws;
    float*  esq      = (float*)((char*)d_ws + 8);

    (void)hipMemsetAsync(d_ws, 0, 8, stream);
    vq_prep<<<2, 256, 0, stream>>>(emb, esq);
    vq_main<<<VQ_MH / 256, 256, 0, stream>>>(z_e, emb, esq, out, loss_acc);
    vq_fin<<<1, 64, 0, stream>>>(loss_acc, out);
}